// Round 10
// baseline (242.626 us; speedup 1.0000x reference)
//
#include <hip/hip_runtime.h>

// B=2, S=4096, C=2048, HD=128, H=16
// GEMM: M=8192 (B*S), N=6144 (3*C), K=2048; out = concat(q,k,v) f32 [8192,2048] each.
// R10: 1024-thread block, 256^2 tile, per-wave 64x64 -> ~110 regs -> 4 waves/SIMD.

#define M_DIM 8192
#define N_DIM 6144
#define K_DIM 2048
#define NKT 32            // K tiles of 64
#define EPS_RMS 1.1920929e-07f

typedef __bf16 bf16x8 __attribute__((ext_vector_type(8)));
typedef float f32x4 __attribute__((ext_vector_type(4)));

__device__ __forceinline__ void gload16(const void* g, void* l) {
  __builtin_amdgcn_global_load_lds(
      (const __attribute__((address_space(1))) unsigned int*)g,
      (__attribute__((address_space(3))) unsigned int*)l, 16, 0, 0);
}

__device__ __forceinline__ unsigned short f2bf(float f) {
  union { float f; unsigned u; } x; x.f = f;
  unsigned r = x.u + 0x7FFFu + ((x.u >> 16) & 1u);   // RNE
  return (unsigned short)(r >> 16);
}

// One launch converts x (16M floats) and wq|wk|wv (3 x 4M floats) to bf16.
__global__ void __launch_bounds__(256) cvt_all(
    const float* __restrict__ x, const float* __restrict__ wq,
    const float* __restrict__ wk, const float* __restrict__ wv,
    unsigned short* __restrict__ xbf, unsigned short* __restrict__ wbf) {
  const int nx4 = M_DIM * K_DIM / 4;
  const int nw4 = K_DIM * K_DIM / 4;
  const int tot = nx4 + 3 * nw4;
  int i = blockIdx.x * blockDim.x + threadIdx.x;
  const int stride = gridDim.x * blockDim.x;
  for (; i < tot; i += stride) {
    const float* s;
    unsigned short* d;
    int j;
    if (i < nx4) { s = x; d = xbf; j = i; }
    else {
      const int k = i - nx4;
      const int sel = k / nw4;
      j = k - sel * nw4;
      s = sel == 0 ? wq : (sel == 1 ? wk : wv);
      d = wbf + (size_t)sel * K_DIM * K_DIM;
    }
    const float4 v = reinterpret_cast<const float4*>(s)[j];
    ushort4 o;
    o.x = f2bf(v.x); o.y = f2bf(v.y); o.z = f2bf(v.z); o.w = f2bf(v.w);
    reinterpret_cast<ushort4*>(d)[j] = o;
  }
}

#define LDS4(ARR, BASE, OFF) (*(const f32x4*)((const char*)(ARR) + (BASE) + (OFF)))

// sched_group_barrier masks: MFMA=0x8, DS_READ=0x100
#define SGB_DS(N)   __builtin_amdgcn_sched_group_barrier(0x100, (N), 0)
#define SGB_MFMA(N) __builtin_amdgcn_sched_group_barrier(0x8, (N), 0)

// One k-slice: 16 independent MFMAs (4 m-frags x 4 n-frags).
#define MFMA_KS()                                                                    \
  {                                                                                  \
    _Pragma("unroll")                                                                \
    for (int mf = 0; mf < 4; ++mf) {                                                 \
      _Pragma("unroll")                                                              \
      for (int nf = 0; nf < 4; ++nf) {                                               \
        acc[mf][nf] = __builtin_amdgcn_mfma_f32_16x16x32_bf16(                       \
            __builtin_bit_cast(bf16x8, Af[mf]),                                      \
            __builtin_bit_cast(bf16x8, Bf[nf]), acc[mf][nf], 0, 0, 0);               \
      }                                                                              \
    }                                                                                \
  }

#define FENCE asm volatile("" ::: "memory")

// 256x256 tile, BK=64, 16 waves (4M x 4N), per-wave 64x64, 16x16x32 MFMA.
// LDS: A[2 buf][2 kslice][256 rows][32 k] bf16 = 64 KB; B same = 64 KB.
// 2 phases/kt (k-slices), 2 barriers/kt, counted vmcnt(2) ledger:
//   ph0 reads ks0 (4A+4B), stages {A,B} ks0(kt+1); wait vmcnt(2) [drains kt ks1]
//   ph1 reads ks1,        stages {A,B} ks1(kt+1); wait vmcnt(2) [drains kt+1 ks0]
// Swizzle for [256][32] unit: slot = lhi ^ ((l15>>1)&3); stage chunk ^= (row>>1)&3.
// Per 16-lane quarter: (row&1, slot) covers all 8 bank-groups 2x -> 2-way = free.
__global__ void __launch_bounds__(1024, 4) gemm_fused(
    const unsigned short* __restrict__ xbf, const unsigned short* __restrict__ wbf,
    const float* __restrict__ rope,
    const float* __restrict__ bq, const float* __restrict__ bk, const float* __restrict__ bv,
    const float* __restrict__ qnw, const float* __restrict__ knw,
    float* __restrict__ dout) {
  const int id = blockIdx.x;
  // XCD-aware, bm-inner: XCD x owns bm in [4x,4x+4), bm fastest -> small L2 set.
  const int xcd = id & 7;
  const int jb = id >> 3;                // 0..95
  const int bm = (xcd << 2) | (jb & 3);  // 0..31
  const int bn = jb >> 2;                // 0..23
  const int m0 = bm << 8, n0 = bn << 8;
  const int tid = threadIdx.x;
  const int w = tid >> 6, l = tid & 63;
  const int l15 = l & 15, lhi = l >> 4;
  const int wr = w >> 2, wc = w & 3;

  __shared__ __align__(16) unsigned short As[32768];   // 64 KB
  __shared__ __align__(16) unsigned short Bs[32768];   // 64 KB

  // ---- staging: unit = 256 rows x 32 k = 16 KB = 1 gload16/thread ----
  const int srow = tid >> 2;                       // 0..255
  const int sch = (tid & 3) ^ ((tid >> 3) & 3);    // chunk ^ (row>>1)&3 involution
  const unsigned short* aSrc = xbf + ((size_t)(m0 + srow) << 11) + (sch << 3);
  const unsigned short* bSrc = wbf + ((size_t)(n0 + srow) << 11) + (sch << 3);
  char* aDst = (char*)As + (w << 10);
  char* bDst = (char*)Bs + (w << 10);

#define STAK(KT, KS) gload16(aSrc + ((KT) << 6) + ((KS) << 5), aDst + ((((KT) & 1) << 15) + ((KS) << 14)))
#define STBK(KT, KS) gload16(bSrc + ((KT) << 6) + ((KS) << 5), bDst + ((((KT) & 1) << 15) + ((KS) << 14)))

  // ---- read-side bases: byte = row*64 + slot*16, slot = lhi ^ ((l15>>1)&3) ----
  const int slot = lhi ^ ((l15 >> 1) & 3);
  unsigned aRd = (wr << 12) + (l15 << 6) + (slot << 4);   // + mf*1024 + ks*16384
  unsigned bRd = (wc << 12) + (l15 << 6) + (slot << 4);   // + nf*1024 + ks*16384

  f32x4 acc[4][4];
#pragma unroll
  for (int i = 0; i < 4; ++i)
#pragma unroll
    for (int jj = 0; jj < 4; ++jj) acc[i][jj] = (f32x4){0.f, 0.f, 0.f, 0.f};

  f32x4 Af[4], Bf[4];

  // ---- prologue: kt0 ks0 then ks1; drain ks0 pair, keep ks1 in flight ----
  STAK(0, 0); STBK(0, 0);
  STAK(0, 1); STBK(0, 1);
  asm volatile("s_waitcnt vmcnt(2)" ::: "memory");
  __builtin_amdgcn_s_barrier();
  FENCE;

  for (int kt = 0; kt < NKT; ++kt) {
    const bool nl = (kt < NKT - 1);
    // ================ phase 0 : k-slice 0 ================
    Af[0] = LDS4(As, aRd, 0);    Bf[0] = LDS4(Bs, bRd, 0);
    Af[1] = LDS4(As, aRd, 1024); Bf[1] = LDS4(Bs, bRd, 1024);
    Af[2] = LDS4(As, aRd, 2048); Bf[2] = LDS4(Bs, bRd, 2048);
    Af[3] = LDS4(As, aRd, 3072); Bf[3] = LDS4(Bs, bRd, 3072);
    if (nl) { STAK(kt + 1, 0); STBK(kt + 1, 0); }
    __builtin_amdgcn_s_setprio(1);
    MFMA_KS();
    SGB_DS(4); SGB_MFMA(2);
    SGB_DS(2); SGB_MFMA(1);
    SGB_DS(2); SGB_MFMA(13);
    __builtin_amdgcn_s_setprio(0);
    if (nl) { asm volatile("s_waitcnt vmcnt(2)" ::: "memory"); }   // drains kt ks1
    else    { asm volatile("s_waitcnt vmcnt(0)" ::: "memory"); }
    __builtin_amdgcn_s_barrier();
    FENCE;
    // ================ phase 1 : k-slice 1 ================
    Af[0] = LDS4(As, aRd, 16384); Bf[0] = LDS4(Bs, bRd, 16384);
    Af[1] = LDS4(As, aRd, 17408); Bf[1] = LDS4(Bs, bRd, 17408);
    Af[2] = LDS4(As, aRd, 18432); Bf[2] = LDS4(Bs, bRd, 18432);
    Af[3] = LDS4(As, aRd, 19456); Bf[3] = LDS4(Bs, bRd, 19456);
    if (nl) { STAK(kt + 1, 1); STBK(kt + 1, 1); }
    __builtin_amdgcn_s_setprio(1);
    MFMA_KS();
    SGB_DS(4); SGB_MFMA(2);
    SGB_DS(2); SGB_MFMA(1);
    SGB_DS(2); SGB_MFMA(13);
    __builtin_amdgcn_s_setprio(0);
    if (nl) { asm volatile("s_waitcnt vmcnt(2)" ::: "memory"); }   // drains kt+1 ks0
    __builtin_amdgcn_s_barrier();
    FENCE;
    aRd ^= 32768u; bRd ^= 32768u;
  }

  // ---- fused epilogue: bias (+ per-head RMSNorm + RoPE for q,k) ----
  float* scr = (float*)As;                       // [16 waves][64 rows] partials
  const int sec = bn >> 3;                       // 0=q 1=k 2=v
  const int nsec = (n0 & 2047) + (wc << 6);      // col-in-section base (+nf*16+l15)
  const float* bias = sec == 0 ? bq : (sec == 1 ? bk : bv);
  float biasv[4];
#pragma unroll
  for (int nf = 0; nf < 4; ++nf) biasv[nf] = bias[nsec + nf * 16 + l15];
  const size_t outBase = ((size_t)sec << 24);

  if (sec < 2) {
    const float* nwp = sec ? knw : qnw;
    const int colh = (wc & 1) << 6;              // col-in-head base for this wave
    float nwv[4];
#pragma unroll
    for (int nf = 0; nf < 4; ++nf) nwv[nf] = nwp[colh + nf * 16 + l15];
    float ssv[4][4];
#pragma unroll
    for (int mf = 0; mf < 4; ++mf) {
#pragma unroll
      for (int jj = 0; jj < 4; ++jj) {
        float ss = 0.f;
#pragma unroll
        for (int nf = 0; nf < 4; ++nf) {
          const float t = acc[mf][nf][jj] + biasv[nf];
          ss += t * t;
        }
        ss += __shfl_xor(ss, 1);
        ss += __shfl_xor(ss, 2);
        ss += __shfl_xor(ss, 4);
        ss += __shfl_xor(ss, 8);
        ssv[mf][jj] = ss;                        // sum over this wave's 64 cols
      }
    }
    if (l15 == 0) {
#pragma unroll
      for (int mf = 0; mf < 4; ++mf)
#pragma unroll
        for (int jj = 0; jj < 4; ++jj)
          scr[(w << 6) + (mf << 4) + (lhi << 2) + jj] = ssv[mf][jj];
    }
    __syncthreads();
#pragma unroll
    for (int mf = 0; mf < 4; ++mf) {
#pragma unroll
      for (int jj = 0; jj < 4; ++jj) {
        const float tot = ssv[mf][jj] + scr[((w ^ 1) << 6) + (mf << 4) + (lhi << 2) + jj];
        const float inv = rsqrtf(tot * (1.0f / 128.0f) + EPS_RMS);
        const int m = m0 + (wr << 6) + (mf << 4) + (lhi << 2) + jj;
        const float* rp = rope + ((size_t)(m & 4095) << 8);
        float* orow = dout + outBase + ((size_t)m << 11) + nsec + l15;
#pragma unroll
        for (int nf = 0; nf < 4; ++nf) {
          const float tn = (acc[mf][nf][jj] + biasv[nf]) * inv * nwv[nf];
          const float pn = __shfl_xor(tn, 1);     // partner col^1
          const int ch = colh + nf * 16 + l15;    // col in head
          const int jr = ch >> 1;
          const float o = fmaf(rp[jr << 2], tn, rp[(jr << 2) + 1 + (ch & 1)] * pn);
          orow[nf << 4] = o;
        }
      }
    }
  } else {
#pragma unroll
    for (int mf = 0; mf < 4; ++mf)
#pragma unroll
      for (int jj = 0; jj < 4; ++jj) {
        const int m = m0 + (wr << 6) + (mf << 4) + (lhi << 2) + jj;
        float* orow = dout + outBase + ((size_t)m << 11) + nsec + l15;
#pragma unroll
        for (int nf = 0; nf < 4; ++nf) orow[nf << 4] = acc[mf][nf][jj] + biasv[nf];
      }
  }
}

extern "C" void kernel_launch(void* const* d_in, const int* in_sizes, int n_in,
                              void* d_out, int out_size, void* d_ws, size_t ws_size,
                              hipStream_t stream) {
  const float* x = (const float*)d_in[0];
  const float* rope = (const float*)d_in[1];
  const float* wq = (const float*)d_in[2];
  const float* bq = (const float*)d_in[3];
  const float* wk = (const float*)d_in[4];
  const float* bk = (const float*)d_in[5];
  const float* wv = (const float*)d_in[6];
  const float* bv = (const float*)d_in[7];
  const float* qnw = (const float*)d_in[8];
  const float* knw = (const float*)d_in[9];

  unsigned short* xbf = (unsigned short*)d_ws;                 // 32 MB
  unsigned short* wbf = xbf + (size_t)M_DIM * K_DIM;           // 24 MB

  cvt_all<<<2048, 256, 0, stream>>>(x, wq, wk, wv, xbf, wbf);

  gemm_fused<<<(M_DIM / 256) * (N_DIM / 256), 1024, 0, stream>>>(
      xbf, wbf, rope, bq, bk, bv, qnw, knw, (float*)d_out);
}

// Round 11
// 241.468 us; speedup vs baseline: 1.0048x; 1.0048x over previous
//
#include <hip/hip_runtime.h>

// B=2, S=4096, C=2048, HD=128, H=16
// GEMM: M=8192 (B*S), N=6144 (3*C), K=2048; out = concat(q,k,v) f32 [8192,2048] each.
// R11: m201-style 4-phase (mh,nh)-quadrant snake, 2 barriers/phase,
//      lgkmcnt(0) after barrier, 2 gloads/phase, waits vmcnt(4)@ph1 / vmcnt(2)@ph3.

#define M_DIM 8192
#define N_DIM 6144
#define K_DIM 2048
#define NKT 32            // K tiles of 64
#define EPS_RMS 1.1920929e-07f

typedef __bf16 bf16x8 __attribute__((ext_vector_type(8)));
typedef float f32x4 __attribute__((ext_vector_type(4)));

__device__ __forceinline__ void gload16(const void* g, void* l) {
  __builtin_amdgcn_global_load_lds(
      (const __attribute__((address_space(1))) unsigned int*)g,
      (__attribute__((address_space(3))) unsigned int*)l, 16, 0, 0);
}

__device__ __forceinline__ unsigned short f2bf(float f) {
  union { float f; unsigned u; } x; x.f = f;
  unsigned r = x.u + 0x7FFFu + ((x.u >> 16) & 1u);   // RNE
  return (unsigned short)(r >> 16);
}

// One launch converts x (16M floats) and wq|wk|wv (3 x 4M floats) to bf16.
__global__ void __launch_bounds__(256) cvt_all(
    const float* __restrict__ x, const float* __restrict__ wq,
    const float* __restrict__ wk, const float* __restrict__ wv,
    unsigned short* __restrict__ xbf, unsigned short* __restrict__ wbf) {
  const int nx4 = M_DIM * K_DIM / 4;
  const int nw4 = K_DIM * K_DIM / 4;
  const int tot = nx4 + 3 * nw4;
  int i = blockIdx.x * blockDim.x + threadIdx.x;
  const int stride = gridDim.x * blockDim.x;
  for (; i < tot; i += stride) {
    const float* s;
    unsigned short* d;
    int j;
    if (i < nx4) { s = x; d = xbf; j = i; }
    else {
      const int k = i - nx4;
      const int sel = k / nw4;
      j = k - sel * nw4;
      s = sel == 0 ? wq : (sel == 1 ? wk : wv);
      d = wbf + (size_t)sel * K_DIM * K_DIM;
    }
    const float4 v = reinterpret_cast<const float4*>(s)[j];
    ushort4 o;
    o.x = f2bf(v.x); o.y = f2bf(v.y); o.z = f2bf(v.z); o.w = f2bf(v.w);
    reinterpret_cast<ushort4*>(d)[j] = o;
  }
}

#define LDS4(ARR, BASE, OFF) (*(const f32x4*)((const char*)(ARR) + (BASE) + (OFF)))

#define MFMA_PH(MH, NH)                                                              \
  {                                                                                  \
    _Pragma("unroll")                                                                \
    for (int mf4 = 0; mf4 < 4; ++mf4) {                                              \
      _Pragma("unroll")                                                              \
      for (int nf2 = 0; nf2 < 2; ++nf2) {                                            \
        f32x4& c = acc[(MH) * 4 + mf4][(NH) * 2 + nf2];                              \
        c = __builtin_amdgcn_mfma_f32_16x16x32_bf16(                                 \
            __builtin_bit_cast(bf16x8, Af[mf4][0]),                                  \
            __builtin_bit_cast(bf16x8, Bf[NH][nf2][0]), c, 0, 0, 0);                 \
        c = __builtin_amdgcn_mfma_f32_16x16x32_bf16(                                 \
            __builtin_bit_cast(bf16x8, Af[mf4][1]),                                  \
            __builtin_bit_cast(bf16x8, Bf[NH][nf2][1]), c, 0, 0, 0);                 \
      }                                                                              \
    }                                                                                \
  }

#define FENCE asm volatile("" ::: "memory")

// Phase epilogue: barrier -> lgkm drain (reads completed during barrier wait)
// -> pinned -> prioritized MFMA cluster.
#define PHASE_MFMA(MH, NH)                          \
  FENCE;                                            \
  __builtin_amdgcn_s_barrier();                     \
  asm volatile("s_waitcnt lgkmcnt(0)" ::: "memory");\
  __builtin_amdgcn_sched_barrier(0);                \
  __builtin_amdgcn_s_setprio(1);                    \
  MFMA_PH(MH, NH);                                  \
  __builtin_amdgcn_s_setprio(0);

// 256x256 tile, BK=64, 8 waves (2M x 4N), per-wave 128x64, 16x16x32 MFMA.
// LDS: A[2 buf][4 quarters][64 rows][64 cols] bf16 = 64 KB; B same = 64 KB.
// 4 phases/kt, snake (0,0)->(0,1)->(1,1)->(1,0); reads 12/4/8/0 (24 minimal,
// B held in regs); stage 2 gloads EVERY phase: B01,B23,A02,A13 (slack >= 2 ph);
// waits: end-ph1 vmcnt(4) [drains this-kt Aq1,Aq3], end-ph3 vmcnt(2)
// [drains kt+1's 6-set], never 0 mid-loop. 2 barriers/phase.
__global__ void __launch_bounds__(512, 2) gemm_fused(
    const unsigned short* __restrict__ xbf, const unsigned short* __restrict__ wbf,
    const float* __restrict__ rope,
    const float* __restrict__ bq, const float* __restrict__ bk, const float* __restrict__ bv,
    const float* __restrict__ qnw, const float* __restrict__ knw,
    float* __restrict__ dout) {
  const int id = blockIdx.x;
  // XCD-aware, bm-inner: XCD x owns bm in [4x,4x+4), bm fastest -> small L2 set.
  const int xcd = id & 7;
  const int jb = id >> 3;                // 0..95
  const int bm = (xcd << 2) | (jb & 3);  // 0..31
  const int bn = jb >> 2;                // 0..23
  const int m0 = bm << 8, n0 = bn << 8;
  const int tid = threadIdx.x;
  const int w = tid >> 6, l = tid & 63;
  const int l15 = l & 15, lhi = l >> 4;
  const int wr = w >> 2, wc = w & 3;

  __shared__ __align__(16) unsigned short As[32768];   // 64 KB
  __shared__ __align__(16) unsigned short Bs[32768];   // 64 KB

  // ---- staging (linear LDS dest, inverse-swizzled global source) ----
  const int srow = tid >> 3;                       // 0..63 within a quarter
  const int schunk = (tid & 7) ^ (srow & 7);       // involution
  const unsigned short* aSrc = xbf + ((size_t)(m0 + srow) << 11) + (schunk << 3);
  const unsigned short* bSrc = wbf + ((size_t)(n0 + srow) << 11) + (schunk << 3);
  char* aDst = (char*)As + (w << 10);
  char* bDst = (char*)Bs + (w << 10);

#define STA(KT, Q) gload16(aSrc + ((size_t)(Q) << 17) + ((KT) << 6), aDst + ((((KT) & 1) << 15) + ((Q) << 13)))
#define STB(KT, Q) gload16(bSrc + ((size_t)(Q) << 17) + ((KT) << 6), bDst + ((((KT) & 1) << 15) + ((Q) << 13)))

  // ---- read-side swizzled byte offsets (k-slot XOR row&7) ----
  const int sl0 = ((lhi ^ (l15 & 7)) << 4);        // k-slots 0..3  (k 0..31)
  const int sl1 = (((lhi + 4) ^ (l15 & 7)) << 4);  // k-slots 4..7  (k 32..63)
  unsigned a0 = (wr << 14) + (l15 << 7) + sl0;
  unsigned a1 = (wr << 14) + (l15 << 7) + sl1;
  unsigned b0 = (wc << 13) + (l15 << 7) + sl0;
  unsigned b1 = (wc << 13) + (l15 << 7) + sl1;

  f32x4 acc[8][4];
#pragma unroll
  for (int i = 0; i < 8; ++i)
#pragma unroll
    for (int jj = 0; jj < 4; ++jj) acc[i][jj] = (f32x4){0.f, 0.f, 0.f, 0.f};

  f32x4 Af[4][2];        // current m-half A fragments (k-slices 0/1)
  f32x4 Bf[2][2][2];     // both B col-halves, held across the K-tile

  // ---- prologue: kt0's sets in deadline order; drain 6, keep Aq1/Aq3 flying ----
  STB(0, 0); STB(0, 1); STB(0, 2); STB(0, 3);
  STA(0, 0); STA(0, 2);
  STA(0, 1); STA(0, 3);
  asm volatile("s_waitcnt vmcnt(2)" ::: "memory");
  __builtin_amdgcn_s_barrier();
  FENCE;

  for (int kt = 0; kt < NKT; ++kt) {
    const bool nl = (kt < NKT - 1);
    // ---- phase 0 (mh0,nh0): A q(2wr) 8r + B nh0 4r; stage B01(kt+1) ----
    Af[0][0] = LDS4(As, a0, 0);        Af[0][1] = LDS4(As, a1, 0);
    Af[1][0] = LDS4(As, a0, 2048);     Af[1][1] = LDS4(As, a1, 2048);
    Af[2][0] = LDS4(As, a0, 4096);     Af[2][1] = LDS4(As, a1, 4096);
    Af[3][0] = LDS4(As, a0, 6144);     Af[3][1] = LDS4(As, a1, 6144);
    Bf[0][0][0] = LDS4(Bs, b0, 0);     Bf[0][0][1] = LDS4(Bs, b1, 0);
    Bf[0][1][0] = LDS4(Bs, b0, 2048);  Bf[0][1][1] = LDS4(Bs, b1, 2048);
    if (nl) { STB(kt + 1, 0); STB(kt + 1, 1); }
    PHASE_MFMA(0, 0);
    __builtin_amdgcn_s_barrier();
    // ---- phase 1 (mh0,nh1): B nh1 4r; stage B23(kt+1) ----
    Bf[1][0][0] = LDS4(Bs, b0, 4096);  Bf[1][0][1] = LDS4(Bs, b1, 4096);
    Bf[1][1][0] = LDS4(Bs, b0, 6144);  Bf[1][1][1] = LDS4(Bs, b1, 6144);
    if (nl) { STB(kt + 1, 2); STB(kt + 1, 3); }
    PHASE_MFMA(0, 1);
    // W1: this-kt Aq1,Aq3 (issued last kt ph3, 2-phase slack) must be visible.
    if (nl) { asm volatile("s_waitcnt vmcnt(4)" ::: "memory"); }
    else    { asm volatile("s_waitcnt vmcnt(0)" ::: "memory"); }
    __builtin_amdgcn_s_barrier();
    // ---- phase 2 (mh1,nh1): A q(2wr+1) 8r; stage A02(kt+1) ----
    Af[0][0] = LDS4(As, a0, 8192);  Af[0][1] = LDS4(As, a1, 8192);
    Af[1][0] = LDS4(As, a0, 10240); Af[1][1] = LDS4(As, a1, 10240);
    Af[2][0] = LDS4(As, a0, 12288); Af[2][1] = LDS4(As, a1, 12288);
    Af[3][0] = LDS4(As, a0, 14336); Af[3][1] = LDS4(As, a1, 14336);
    if (nl) { STA(kt + 1, 0); STA(kt + 1, 2); }
    PHASE_MFMA(1, 1);
    __builtin_amdgcn_s_barrier();
    // ---- phase 3 (mh1,nh0): 0 reads (A,B in regs); stage A13(kt+1) ----
    if (nl) { STA(kt + 1, 1); STA(kt + 1, 3); }
    PHASE_MFMA(1, 0);
    // W2: kt+1's 6-set (B0123 + A02) must be visible; leave A13 in flight.
    if (nl) { asm volatile("s_waitcnt vmcnt(2)" ::: "memory"); }
    __builtin_amdgcn_s_barrier();
    FENCE;
    a0 ^= 32768u; a1 ^= 32768u; b0 ^= 32768u; b1 ^= 32768u;
  }

  // ---- fused epilogue: bias (+ per-head RMSNorm + RoPE for q,k) ----
  float* scr = (float*)As;                       // [8 waves][128 rows] partials
  const int sec = bn >> 3;                       // 0=q 1=k 2=v
  const int nsec = (n0 & 2047) + (wc << 6);      // col-in-section base (+nf*16+l15)
  const float* bias = sec == 0 ? bq : (sec == 1 ? bk : bv);
  float biasv[4];
#pragma unroll
  for (int nf = 0; nf < 4; ++nf) biasv[nf] = bias[nsec + nf * 16 + l15];
  const size_t outBase = ((size_t)sec << 24);

  if (sec < 2) {
    const float* nwp = sec ? knw : qnw;
    const int colh = (wc & 1) << 6;              // col-in-head base for this wave
    float nwv[4];
#pragma unroll
    for (int nf = 0; nf < 4; ++nf) nwv[nf] = nwp[colh + nf * 16 + l15];
    float ssv[8][4];
#pragma unroll
    for (int mf = 0; mf < 8; ++mf) {
#pragma unroll
      for (int jj = 0; jj < 4; ++jj) {
        float ss = 0.f;
#pragma unroll
        for (int nf = 0; nf < 4; ++nf) {
          const float t = acc[mf][nf][jj] + biasv[nf];
          ss += t * t;
        }
        ss += __shfl_xor(ss, 1);
        ss += __shfl_xor(ss, 2);
        ss += __shfl_xor(ss, 4);
        ss += __shfl_xor(ss, 8);
        ssv[mf][jj] = ss;                        // sum over this wave's 64 cols
      }
    }
    if (l15 == 0) {
#pragma unroll
      for (int mf = 0; mf < 8; ++mf)
#pragma unroll
        for (int jj = 0; jj < 4; ++jj)
          scr[(w << 7) + mf * 16 + (lhi << 2) + jj] = ssv[mf][jj];
    }
    __syncthreads();
#pragma unroll
    for (int mf = 0; mf < 8; ++mf) {
#pragma unroll
      for (int jj = 0; jj < 4; ++jj) {
        const float tot = ssv[mf][jj] + scr[((w ^ 1) << 7) + mf * 16 + (lhi << 2) + jj];
        const float inv = rsqrtf(tot * (1.0f / 128.0f) + EPS_RMS);
        const int m = m0 + (wr << 7) + mf * 16 + (lhi << 2) + jj;
        const float* rp = rope + ((size_t)(m & 4095) << 8);
        float* orow = dout + outBase + ((size_t)m << 11) + nsec + l15;
#pragma unroll
        for (int nf = 0; nf < 4; ++nf) {
          const float tn = (acc[mf][nf][jj] + biasv[nf]) * inv * nwv[nf];
          const float pn = __shfl_xor(tn, 1);     // partner col^1
          const int ch = colh + nf * 16 + l15;    // col in head
          const int jr = ch >> 1;
          const float o = fmaf(rp[jr << 2], tn, rp[(jr << 2) + 1 + (ch & 1)] * pn);
          orow[nf << 4] = o;
        }
      }
    }
  } else {
#pragma unroll
    for (int mf = 0; mf < 8; ++mf)
#pragma unroll
      for (int jj = 0; jj < 4; ++jj) {
        const int m = m0 + (wr << 7) + mf * 16 + (lhi << 2) + jj;
        float* orow = dout + outBase + ((size_t)m << 11) + nsec + l15;
#pragma unroll
        for (int nf = 0; nf < 4; ++nf) orow[nf << 4] = acc[mf][nf][jj] + biasv[nf];
      }
  }
}

extern "C" void kernel_launch(void* const* d_in, const int* in_sizes, int n_in,
                              void* d_out, int out_size, void* d_ws, size_t ws_size,
                              hipStream_t stream) {
  const float* x = (const float*)d_in[0];
  const float* rope = (const float*)d_in[1];
  const float* wq = (const float*)d_in[2];
  const float* bq = (const float*)d_in[3];
  const float* wk = (const float*)d_in[4];
  const float* bk = (const float*)d_in[5];
  const float* wv = (const float*)d_in[6];
  const float* bv = (const float*)d_in[7];
  const float* qnw = (const float*)d_in[8];
  const float* knw = (const float*)d_in[9];

  unsigned short* xbf = (unsigned short*)d_ws;                 // 32 MB
  unsigned short* wbf = xbf + (size_t)M_DIM * K_DIM;           // 24 MB

  cvt_all<<<2048, 256, 0, stream>>>(x, wq, wk, wv, xbf, wbf);

  gemm_fused<<<(M_DIM / 256) * (N_DIM / 256), 512, 0, stream>>>(
      xbf, wbf, rope, bq, bk, bv, qnw, knw, (float*)d_out);
}

// Round 12
// 234.170 us; speedup vs baseline: 1.0361x; 1.0312x over previous
//
#include <hip/hip_runtime.h>

// B=2, S=4096, C=2048, HD=128, H=16
// GEMM: M=8192 (B*S), N=6144 (3*C), K=2048; out = concat(q,k,v) f32 [8192,2048] each.
// R12 = R9 verbatim (session best: 233.9 us total, GEMM 224 us / 920 TF).
//   - bf16 path: fused single-launch f32->bf16 conversion of x and W into d_ws
//   - 256x256 tile, BK=64, 8 waves (2M x 4N), per-wave 128x64, 16x16x32 MFMA
//   - global_load_lds width-16 staging, both-sides XOR swizzle (0 bank conflicts)
//   - 2 phases/K-tile, 2 barriers/K-tile, counted vmcnt(6)/vmcnt(2) ledger
//   - sched_group_barrier DS/MFMA interleave, setprio around MFMA clusters
//   - bm-inner XCD swizzle (FETCH 400->157 MB), fused bias+RMSNorm+RoPE epilogue

#define M_DIM 8192
#define N_DIM 6144
#define K_DIM 2048
#define NKT 32            // K tiles of 64
#define EPS_RMS 1.1920929e-07f

typedef __bf16 bf16x8 __attribute__((ext_vector_type(8)));
typedef float f32x4 __attribute__((ext_vector_type(4)));

__device__ __forceinline__ void gload16(const void* g, void* l) {
  __builtin_amdgcn_global_load_lds(
      (const __attribute__((address_space(1))) unsigned int*)g,
      (__attribute__((address_space(3))) unsigned int*)l, 16, 0, 0);
}

__device__ __forceinline__ unsigned short f2bf(float f) {
  union { float f; unsigned u; } x; x.f = f;
  unsigned r = x.u + 0x7FFFu + ((x.u >> 16) & 1u);   // RNE
  return (unsigned short)(r >> 16);
}

// One launch converts x (16M floats) and wq|wk|wv (3 x 4M floats) to bf16.
__global__ void __launch_bounds__(256) cvt_all(
    const float* __restrict__ x, const float* __restrict__ wq,
    const float* __restrict__ wk, const float* __restrict__ wv,
    unsigned short* __restrict__ xbf, unsigned short* __restrict__ wbf) {
  const int nx4 = M_DIM * K_DIM / 4;
  const int nw4 = K_DIM * K_DIM / 4;
  const int tot = nx4 + 3 * nw4;
  int i = blockIdx.x * blockDim.x + threadIdx.x;
  const int stride = gridDim.x * blockDim.x;
  for (; i < tot; i += stride) {
    const float* s;
    unsigned short* d;
    int j;
    if (i < nx4) { s = x; d = xbf; j = i; }
    else {
      const int k = i - nx4;
      const int sel = k / nw4;
      j = k - sel * nw4;
      s = sel == 0 ? wq : (sel == 1 ? wk : wv);
      d = wbf + (size_t)sel * K_DIM * K_DIM;
    }
    const float4 v = reinterpret_cast<const float4*>(s)[j];
    ushort4 o;
    o.x = f2bf(v.x); o.y = f2bf(v.y); o.z = f2bf(v.z); o.w = f2bf(v.w);
    reinterpret_cast<ushort4*>(d)[j] = o;
  }
}

#define LDS4(ARR, BASE, OFF) (*(const f32x4*)((const char*)(ARR) + (BASE) + (OFF)))

// sched_group_barrier masks: MFMA=0x8, DS_READ=0x100
#define SGB_DS(N)   __builtin_amdgcn_sched_group_barrier(0x100, (N), 0)
#define SGB_MFMA(N) __builtin_amdgcn_sched_group_barrier(0x8, (N), 0)

#define MFMA_PH(MH, NH)                                                              \
  {                                                                                  \
    _Pragma("unroll")                                                                \
    for (int mf4 = 0; mf4 < 4; ++mf4) {                                              \
      _Pragma("unroll")                                                              \
      for (int nf2 = 0; nf2 < 2; ++nf2) {                                            \
        f32x4& c = acc[(MH) * 4 + mf4][(NH) * 2 + nf2];                              \
        c = __builtin_amdgcn_mfma_f32_16x16x32_bf16(                                 \
            __builtin_bit_cast(bf16x8, Af[mf4][0]),                                  \
            __builtin_bit_cast(bf16x8, Bf[NH][nf2][0]), c, 0, 0, 0);                 \
        c = __builtin_amdgcn_mfma_f32_16x16x32_bf16(                                 \
            __builtin_bit_cast(bf16x8, Af[mf4][1]),                                  \
            __builtin_bit_cast(bf16x8, Bf[NH][nf2][1]), c, 0, 0, 0);                 \
      }                                                                              \
    }                                                                                \
  }

#define FENCE asm volatile("" ::: "memory")

__global__ void __launch_bounds__(512, 2) gemm_fused(
    const unsigned short* __restrict__ xbf, const unsigned short* __restrict__ wbf,
    const float* __restrict__ rope,
    const float* __restrict__ bq, const float* __restrict__ bk, const float* __restrict__ bv,
    const float* __restrict__ qnw, const float* __restrict__ knw,
    float* __restrict__ dout) {
  const int id = blockIdx.x;
  // XCD-aware, bm-inner: XCD x owns bm in [4x,4x+4), bm fastest -> small L2 set.
  const int xcd = id & 7;
  const int jb = id >> 3;                // 0..95
  const int bm = (xcd << 2) | (jb & 3);  // 0..31
  const int bn = jb >> 2;                // 0..23
  const int m0 = bm << 8, n0 = bn << 8;
  const int tid = threadIdx.x;
  const int w = tid >> 6, l = tid & 63;
  const int l15 = l & 15, lhi = l >> 4;
  const int wr = w >> 2, wc = w & 3;

  __shared__ __align__(16) unsigned short As[32768];   // 64 KB
  __shared__ __align__(16) unsigned short Bs[32768];   // 64 KB

  // ---- staging (linear LDS dest, inverse-swizzled global source) ----
  const int srow = tid >> 3;                       // 0..63 within a quarter
  const int schunk = (tid & 7) ^ (srow & 7);       // involution
  const unsigned short* aSrc = xbf + ((size_t)(m0 + srow) << 11) + (schunk << 3);
  const unsigned short* bSrc = wbf + ((size_t)(n0 + srow) << 11) + (schunk << 3);
  char* aDst = (char*)As + (w << 10);
  char* bDst = (char*)Bs + (w << 10);

#define STA(KT, Q) gload16(aSrc + ((size_t)(Q) << 17) + ((KT) << 6), aDst + ((((KT) & 1) << 15) + ((Q) << 13)))
#define STB(KT, Q) gload16(bSrc + ((size_t)(Q) << 17) + ((KT) << 6), bDst + ((((KT) & 1) << 15) + ((Q) << 13)))

  // ---- read-side swizzled byte offsets (k-slot XOR row&7) ----
  const int sl0 = ((lhi ^ (l15 & 7)) << 4);        // k-slots 0..3  (k 0..31)
  const int sl1 = (((lhi + 4) ^ (l15 & 7)) << 4);  // k-slots 4..7  (k 32..63)
  unsigned a0 = (wr << 14) + (l15 << 7) + sl0;
  unsigned a1 = (wr << 14) + (l15 << 7) + sl1;
  unsigned b0 = (wc << 13) + (l15 << 7) + sl0;
  unsigned b1 = (wc << 13) + (l15 << 7) + sl1;

  f32x4 acc[8][4];
#pragma unroll
  for (int i = 0; i < 8; ++i)
#pragma unroll
    for (int jj = 0; jj < 4; ++jj) acc[i][jj] = (f32x4){0.f, 0.f, 0.f, 0.f};

  f32x4 Af[4][2];        // current A-half fragments (k-slices 0/1)
  f32x4 Bf[2][2][2];     // both B col-halves, held across the K-tile

  // ---- prologue: kt0's 6 ph0-needed loads, then its 2 A q1/q3 ----
  STA(0, 0); STA(0, 2);
  STB(0, 0); STB(0, 1); STB(0, 2); STB(0, 3);
  STA(0, 1); STA(0, 3);
  asm volatile("s_waitcnt vmcnt(2)" ::: "memory");
  __builtin_amdgcn_s_barrier();
  FENCE;

  for (int kt = 0; kt < NKT; ++kt) {
    const bool notLast = (kt < NKT - 1);
    // ================ phase 0 : A-h0 + B(all), MFMA Q00,Q01 ================
    Af[0][0] = LDS4(As, a0, 0);        Af[0][1] = LDS4(As, a1, 0);
    Bf[0][0][0] = LDS4(Bs, b0, 0);     Bf[0][0][1] = LDS4(Bs, b1, 0);
    Bf[0][1][0] = LDS4(Bs, b0, 2048);  Bf[0][1][1] = LDS4(Bs, b1, 2048);
    Af[1][0] = LDS4(As, a0, 2048);     Af[1][1] = LDS4(As, a1, 2048);
    Af[2][0] = LDS4(As, a0, 4096);     Af[2][1] = LDS4(As, a1, 4096);
    Af[3][0] = LDS4(As, a0, 6144);     Af[3][1] = LDS4(As, a1, 6144);
    Bf[1][0][0] = LDS4(Bs, b0, 4096);  Bf[1][0][1] = LDS4(Bs, b1, 4096);
    Bf[1][1][0] = LDS4(Bs, b0, 6144);  Bf[1][1][1] = LDS4(Bs, b1, 6144);
    if (notLast) {
      STA(kt + 1, 0); STA(kt + 1, 2);
      STB(kt + 1, 0); STB(kt + 1, 1); STB(kt + 1, 2); STB(kt + 1, 3);
    }
    __builtin_amdgcn_s_setprio(1);
    MFMA_PH(0, 0);
    MFMA_PH(0, 1);
    // forced interleave: {DS4,M2,DS2,M2,DS2,M4,DS2,M4,DS2,M4,DS4,M16}
    SGB_DS(4);  SGB_MFMA(2);
    SGB_DS(2);  SGB_MFMA(2);
    SGB_DS(2);  SGB_MFMA(4);
    SGB_DS(2);  SGB_MFMA(4);
    SGB_DS(2);  SGB_MFMA(4);
    SGB_DS(4);  SGB_MFMA(16);
    __builtin_amdgcn_s_setprio(0);
    if (notLast) { asm volatile("s_waitcnt vmcnt(6)" ::: "memory"); }
    else         { asm volatile("s_waitcnt vmcnt(0)" ::: "memory"); }
    __builtin_amdgcn_s_barrier();
    FENCE;
    // ================ phase 1 : A-h1, MFMA Q10,Q11 (B in regs) ================
    Af[0][0] = LDS4(As, a0, 8192);  Af[0][1] = LDS4(As, a1, 8192);
    Af[1][0] = LDS4(As, a0, 10240); Af[1][1] = LDS4(As, a1, 10240);
    Af[2][0] = LDS4(As, a0, 12288); Af[2][1] = LDS4(As, a1, 12288);
    Af[3][0] = LDS4(As, a0, 14336); Af[3][1] = LDS4(As, a1, 14336);
    if (notLast) { STA(kt + 1, 1); STA(kt + 1, 3); }
    __builtin_amdgcn_s_setprio(1);
    MFMA_PH(1, 0);
    MFMA_PH(1, 1);
    // forced interleave: {DS2,M4}x4, M16
    SGB_DS(2);  SGB_MFMA(4);
    SGB_DS(2);  SGB_MFMA(4);
    SGB_DS(2);  SGB_MFMA(4);
    SGB_DS(2);  SGB_MFMA(4);
    SGB_MFMA(16);
    __builtin_amdgcn_s_setprio(0);
    if (notLast) { asm volatile("s_waitcnt vmcnt(2)" ::: "memory"); }
    __builtin_amdgcn_s_barrier();
    FENCE;
    a0 ^= 32768u; a1 ^= 32768u; b0 ^= 32768u; b1 ^= 32768u;
  }

  // ---- fused epilogue: bias (+ per-head RMSNorm + RoPE for q,k) ----
  float* scr = (float*)As;                       // [8 waves][128 rows] partials
  const int sec = bn >> 3;                       // 0=q 1=k 2=v
  const int nsec = (n0 & 2047) + (wc << 6);      // col-in-section base (+nf*16+l15)
  const float* bias = sec == 0 ? bq : (sec == 1 ? bk : bv);
  float biasv[4];
#pragma unroll
  for (int nf = 0; nf < 4; ++nf) biasv[nf] = bias[nsec + nf * 16 + l15];
  const size_t outBase = ((size_t)sec << 24);

  if (sec < 2) {
    const float* nwp = sec ? knw : qnw;
    const int colh = (wc & 1) << 6;              // col-in-head base for this wave
    float nwv[4];
#pragma unroll
    for (int nf = 0; nf < 4; ++nf) nwv[nf] = nwp[colh + nf * 16 + l15];
    float ssv[8][4];
#pragma unroll
    for (int mf = 0; mf < 8; ++mf) {
#pragma unroll
      for (int jj = 0; jj < 4; ++jj) {
        float ss = 0.f;
#pragma unroll
        for (int nf = 0; nf < 4; ++nf) {
          const float t = acc[mf][nf][jj] + biasv[nf];
          ss += t * t;
        }
        ss += __shfl_xor(ss, 1);
        ss += __shfl_xor(ss, 2);
        ss += __shfl_xor(ss, 4);
        ss += __shfl_xor(ss, 8);
        ssv[mf][jj] = ss;                        // sum over this wave's 64 cols
      }
    }
    if (l15 == 0) {
#pragma unroll
      for (int mf = 0; mf < 8; ++mf)
#pragma unroll
        for (int jj = 0; jj < 4; ++jj)
          scr[(w << 7) + mf * 16 + (lhi << 2) + jj] = ssv[mf][jj];
    }
    __syncthreads();
#pragma unroll
    for (int mf = 0; mf < 8; ++mf) {
#pragma unroll
      for (int jj = 0; jj < 4; ++jj) {
        const float tot = ssv[mf][jj] + scr[((w ^ 1) << 7) + mf * 16 + (lhi << 2) + jj];
        const float inv = rsqrtf(tot * (1.0f / 128.0f) + EPS_RMS);
        const int m = m0 + (wr << 7) + mf * 16 + (lhi << 2) + jj;
        const float* rp = rope + ((size_t)(m & 4095) << 8);
        float* orow = dout + outBase + ((size_t)m << 11) + nsec + l15;
#pragma unroll
        for (int nf = 0; nf < 4; ++nf) {
          const float tn = (acc[mf][nf][jj] + biasv[nf]) * inv * nwv[nf];
          const float pn = __shfl_xor(tn, 1);     // partner col^1
          const int ch = colh + nf * 16 + l15;    // col in head
          const int jr = ch >> 1;
          const float o = fmaf(rp[jr << 2], tn, rp[(jr << 2) + 1 + (ch & 1)] * pn);
          orow[nf << 4] = o;
        }
      }
    }
  } else {
#pragma unroll
    for (int mf = 0; mf < 8; ++mf)
#pragma unroll
      for (int jj = 0; jj < 4; ++jj) {
        const int m = m0 + (wr << 7) + mf * 16 + (lhi << 2) + jj;
        float* orow = dout + outBase + ((size_t)m << 11) + nsec + l15;
#pragma unroll
        for (int nf = 0; nf < 4; ++nf) orow[nf << 4] = acc[mf][nf][jj] + biasv[nf];
      }
  }
}

extern "C" void kernel_launch(void* const* d_in, const int* in_sizes, int n_in,
                              void* d_out, int out_size, void* d_ws, size_t ws_size,
                              hipStream_t stream) {
  const float* x = (const float*)d_in[0];
  const float* rope = (const float*)d_in[1];
  const float* wq = (const float*)d_in[2];
  const float* bq = (const float*)d_in[3];
  const float* wk = (const float*)d_in[4];
  const float* bk = (const float*)d_in[5];
  const float* wv = (const float*)d_in[6];
  const float* bv = (const float*)d_in[7];
  const float* qnw = (const float*)d_in[8];
  const float* knw = (const float*)d_in[9];

  unsigned short* xbf = (unsigned short*)d_ws;                 // 32 MB
  unsigned short* wbf = xbf + (size_t)M_DIM * K_DIM;           // 24 MB

  cvt_all<<<2048, 256, 0, stream>>>(x, wq, wk, wv, xbf, wbf);

  gemm_fused<<<(M_DIM / 256) * (N_DIM / 256), 512, 0, stream>>>(
      xbf, wbf, rope, bq, bk, bv, qnw, knw, (float*)d_out);
}

// Round 13
// 232.501 us; speedup vs baseline: 1.0435x; 1.0072x over previous
//
#include <hip/hip_runtime.h>

// B=2, S=4096, C=2048, HD=128, H=16
// GEMM: M=8192 (B*S), N=6144 (3*C), K=2048; out = concat(q,k,v) f32 [8192,2048] each.
// R13 = R9 with sched_group_barrier REMOVED (isolation test: SGB's marginal value).
// Everything else identical: 256x256 tile, BK=64, 8 waves, 16x16x32 MFMA,
// both-sides XOR swizzle, 2 phases/kt, counted vmcnt(6)/vmcnt(2), setprio,
// bm-inner XCD swizzle, fused single-launch cvt, fused bias+RMSNorm+RoPE epilogue.

#define M_DIM 8192
#define N_DIM 6144
#define K_DIM 2048
#define NKT 32            // K tiles of 64
#define EPS_RMS 1.1920929e-07f

typedef __bf16 bf16x8 __attribute__((ext_vector_type(8)));
typedef float f32x4 __attribute__((ext_vector_type(4)));

__device__ __forceinline__ void gload16(const void* g, void* l) {
  __builtin_amdgcn_global_load_lds(
      (const __attribute__((address_space(1))) unsigned int*)g,
      (__attribute__((address_space(3))) unsigned int*)l, 16, 0, 0);
}

__device__ __forceinline__ unsigned short f2bf(float f) {
  union { float f; unsigned u; } x; x.f = f;
  unsigned r = x.u + 0x7FFFu + ((x.u >> 16) & 1u);   // RNE
  return (unsigned short)(r >> 16);
}

// One launch converts x (16M floats) and wq|wk|wv (3 x 4M floats) to bf16.
__global__ void __launch_bounds__(256) cvt_all(
    const float* __restrict__ x, const float* __restrict__ wq,
    const float* __restrict__ wk, const float* __restrict__ wv,
    unsigned short* __restrict__ xbf, unsigned short* __restrict__ wbf) {
  const int nx4 = M_DIM * K_DIM / 4;
  const int nw4 = K_DIM * K_DIM / 4;
  const int tot = nx4 + 3 * nw4;
  int i = blockIdx.x * blockDim.x + threadIdx.x;
  const int stride = gridDim.x * blockDim.x;
  for (; i < tot; i += stride) {
    const float* s;
    unsigned short* d;
    int j;
    if (i < nx4) { s = x; d = xbf; j = i; }
    else {
      const int k = i - nx4;
      const int sel = k / nw4;
      j = k - sel * nw4;
      s = sel == 0 ? wq : (sel == 1 ? wk : wv);
      d = wbf + (size_t)sel * K_DIM * K_DIM;
    }
    const float4 v = reinterpret_cast<const float4*>(s)[j];
    ushort4 o;
    o.x = f2bf(v.x); o.y = f2bf(v.y); o.z = f2bf(v.z); o.w = f2bf(v.w);
    reinterpret_cast<ushort4*>(d)[j] = o;
  }
}

#define LDS4(ARR, BASE, OFF) (*(const f32x4*)((const char*)(ARR) + (BASE) + (OFF)))

#define MFMA_PH(MH, NH)                                                              \
  {                                                                                  \
    _Pragma("unroll")                                                                \
    for (int mf4 = 0; mf4 < 4; ++mf4) {                                              \
      _Pragma("unroll")                                                              \
      for (int nf2 = 0; nf2 < 2; ++nf2) {                                            \
        f32x4& c = acc[(MH) * 4 + mf4][(NH) * 2 + nf2];                              \
        c = __builtin_amdgcn_mfma_f32_16x16x32_bf16(                                 \
            __builtin_bit_cast(bf16x8, Af[mf4][0]),                                  \
            __builtin_bit_cast(bf16x8, Bf[NH][nf2][0]), c, 0, 0, 0);                 \
        c = __builtin_amdgcn_mfma_f32_16x16x32_bf16(                                 \
            __builtin_bit_cast(bf16x8, Af[mf4][1]),                                  \
            __builtin_bit_cast(bf16x8, Bf[NH][nf2][1]), c, 0, 0, 0);                 \
      }                                                                              \
    }                                                                                \
  }

#define FENCE asm volatile("" ::: "memory")

__global__ void __launch_bounds__(512, 2) gemm_fused(
    const unsigned short* __restrict__ xbf, const unsigned short* __restrict__ wbf,
    const float* __restrict__ rope,
    const float* __restrict__ bq, const float* __restrict__ bk, const float* __restrict__ bv,
    const float* __restrict__ qnw, const float* __restrict__ knw,
    float* __restrict__ dout) {
  const int id = blockIdx.x;
  // XCD-aware, bm-inner: XCD x owns bm in [4x,4x+4), bm fastest -> small L2 set.
  const int xcd = id & 7;
  const int jb = id >> 3;                // 0..95
  const int bm = (xcd << 2) | (jb & 3);  // 0..31
  const int bn = jb >> 2;                // 0..23
  const int m0 = bm << 8, n0 = bn << 8;
  const int tid = threadIdx.x;
  const int w = tid >> 6, l = tid & 63;
  const int l15 = l & 15, lhi = l >> 4;
  const int wr = w >> 2, wc = w & 3;

  __shared__ __align__(16) unsigned short As[32768];   // 64 KB
  __shared__ __align__(16) unsigned short Bs[32768];   // 64 KB

  // ---- staging (linear LDS dest, inverse-swizzled global source) ----
  const int srow = tid >> 3;                       // 0..63 within a quarter
  const int schunk = (tid & 7) ^ (srow & 7);       // involution
  const unsigned short* aSrc = xbf + ((size_t)(m0 + srow) << 11) + (schunk << 3);
  const unsigned short* bSrc = wbf + ((size_t)(n0 + srow) << 11) + (schunk << 3);
  char* aDst = (char*)As + (w << 10);
  char* bDst = (char*)Bs + (w << 10);

#define STA(KT, Q) gload16(aSrc + ((size_t)(Q) << 17) + ((KT) << 6), aDst + ((((KT) & 1) << 15) + ((Q) << 13)))
#define STB(KT, Q) gload16(bSrc + ((size_t)(Q) << 17) + ((KT) << 6), bDst + ((((KT) & 1) << 15) + ((Q) << 13)))

  // ---- read-side swizzled byte offsets (k-slot XOR row&7) ----
  const int sl0 = ((lhi ^ (l15 & 7)) << 4);        // k-slots 0..3  (k 0..31)
  const int sl1 = (((lhi + 4) ^ (l15 & 7)) << 4);  // k-slots 4..7  (k 32..63)
  unsigned a0 = (wr << 14) + (l15 << 7) + sl0;
  unsigned a1 = (wr << 14) + (l15 << 7) + sl1;
  unsigned b0 = (wc << 13) + (l15 << 7) + sl0;
  unsigned b1 = (wc << 13) + (l15 << 7) + sl1;

  f32x4 acc[8][4];
#pragma unroll
  for (int i = 0; i < 8; ++i)
#pragma unroll
    for (int jj = 0; jj < 4; ++jj) acc[i][jj] = (f32x4){0.f, 0.f, 0.f, 0.f};

  f32x4 Af[4][2];        // current A-half fragments (k-slices 0/1)
  f32x4 Bf[2][2][2];     // both B col-halves, held across the K-tile

  // ---- prologue: kt0's 6 ph0-needed loads, then its 2 A q1/q3 ----
  STA(0, 0); STA(0, 2);
  STB(0, 0); STB(0, 1); STB(0, 2); STB(0, 3);
  STA(0, 1); STA(0, 3);
  asm volatile("s_waitcnt vmcnt(2)" ::: "memory");
  __builtin_amdgcn_s_barrier();
  FENCE;

  for (int kt = 0; kt < NKT; ++kt) {
    const bool notLast = (kt < NKT - 1);
    // ================ phase 0 : A-h0 + B(all), MFMA Q00,Q01 ================
    Af[0][0] = LDS4(As, a0, 0);        Af[0][1] = LDS4(As, a1, 0);
    Bf[0][0][0] = LDS4(Bs, b0, 0);     Bf[0][0][1] = LDS4(Bs, b1, 0);
    Bf[0][1][0] = LDS4(Bs, b0, 2048);  Bf[0][1][1] = LDS4(Bs, b1, 2048);
    Af[1][0] = LDS4(As, a0, 2048);     Af[1][1] = LDS4(As, a1, 2048);
    Af[2][0] = LDS4(As, a0, 4096);     Af[2][1] = LDS4(As, a1, 4096);
    Af[3][0] = LDS4(As, a0, 6144);     Af[3][1] = LDS4(As, a1, 6144);
    Bf[1][0][0] = LDS4(Bs, b0, 4096);  Bf[1][0][1] = LDS4(Bs, b1, 4096);
    Bf[1][1][0] = LDS4(Bs, b0, 6144);  Bf[1][1][1] = LDS4(Bs, b1, 6144);
    if (notLast) {
      STA(kt + 1, 0); STA(kt + 1, 2);
      STB(kt + 1, 0); STB(kt + 1, 1); STB(kt + 1, 2); STB(kt + 1, 3);
    }
    __builtin_amdgcn_s_setprio(1);
    MFMA_PH(0, 0);
    MFMA_PH(0, 1);
    __builtin_amdgcn_s_setprio(0);
    if (notLast) { asm volatile("s_waitcnt vmcnt(6)" ::: "memory"); }
    else         { asm volatile("s_waitcnt vmcnt(0)" ::: "memory"); }
    __builtin_amdgcn_s_barrier();
    FENCE;
    // ================ phase 1 : A-h1, MFMA Q10,Q11 (B in regs) ================
    Af[0][0] = LDS4(As, a0, 8192);  Af[0][1] = LDS4(As, a1, 8192);
    Af[1][0] = LDS4(As, a0, 10240); Af[1][1] = LDS4(As, a1, 10240);
    Af[2][0] = LDS4(As, a0, 12288); Af[2][1] = LDS4(As, a1, 12288);
    Af[3][0] = LDS4(As, a0, 14336); Af[3][1] = LDS4(As, a1, 14336);
    if (notLast) { STA(kt + 1, 1); STA(kt + 1, 3); }
    __builtin_amdgcn_s_setprio(1);
    MFMA_PH(1, 0);
    MFMA_PH(1, 1);
    __builtin_amdgcn_s_setprio(0);
    if (notLast) { asm volatile("s_waitcnt vmcnt(2)" ::: "memory"); }
    __builtin_amdgcn_s_barrier();
    FENCE;
    a0 ^= 32768u; a1 ^= 32768u; b0 ^= 32768u; b1 ^= 32768u;
  }

  // ---- fused epilogue: bias (+ per-head RMSNorm + RoPE for q,k) ----
  float* scr = (float*)As;                       // [8 waves][128 rows] partials
  const int sec = bn >> 3;                       // 0=q 1=k 2=v
  const int nsec = (n0 & 2047) + (wc << 6);      // col-in-section base (+nf*16+l15)
  const float* bias = sec == 0 ? bq : (sec == 1 ? bk : bv);
  float biasv[4];
#pragma unroll
  for (int nf = 0; nf < 4; ++nf) biasv[nf] = bias[nsec + nf * 16 + l15];
  const size_t outBase = ((size_t)sec << 24);

  if (sec < 2) {
    const float* nwp = sec ? knw : qnw;
    const int colh = (wc & 1) << 6;              // col-in-head base for this wave
    float nwv[4];
#pragma unroll
    for (int nf = 0; nf < 4; ++nf) nwv[nf] = nwp[colh + nf * 16 + l15];
    float ssv[8][4];
#pragma unroll
    for (int mf = 0; mf < 8; ++mf) {
#pragma unroll
      for (int jj = 0; jj < 4; ++jj) {
        float ss = 0.f;
#pragma unroll
        for (int nf = 0; nf < 4; ++nf) {
          const float t = acc[mf][nf][jj] + biasv[nf];
          ss += t * t;
        }
        ss += __shfl_xor(ss, 1);
        ss += __shfl_xor(ss, 2);
        ss += __shfl_xor(ss, 4);
        ss += __shfl_xor(ss, 8);
        ssv[mf][jj] = ss;                        // sum over this wave's 64 cols
      }
    }
    if (l15 == 0) {
#pragma unroll
      for (int mf = 0; mf < 8; ++mf)
#pragma unroll
        for (int jj = 0; jj < 4; ++jj)
          scr[(w << 7) + mf * 16 + (lhi << 2) + jj] = ssv[mf][jj];
    }
    __syncthreads();
#pragma unroll
    for (int mf = 0; mf < 8; ++mf) {
#pragma unroll
      for (int jj = 0; jj < 4; ++jj) {
        const float tot = ssv[mf][jj] + scr[((w ^ 1) << 7) + mf * 16 + (lhi << 2) + jj];
        const float inv = rsqrtf(tot * (1.0f / 128.0f) + EPS_RMS);
        const int m = m0 + (wr << 7) + mf * 16 + (lhi << 2) + jj;
        const float* rp = rope + ((size_t)(m & 4095) << 8);
        float* orow = dout + outBase + ((size_t)m << 11) + nsec + l15;
#pragma unroll
        for (int nf = 0; nf < 4; ++nf) {
          const float tn = (acc[mf][nf][jj] + biasv[nf]) * inv * nwv[nf];
          const float pn = __shfl_xor(tn, 1);     // partner col^1
          const int ch = colh + nf * 16 + l15;    // col in head
          const int jr = ch >> 1;
          const float o = fmaf(rp[jr << 2], tn, rp[(jr << 2) + 1 + (ch & 1)] * pn);
          orow[nf << 4] = o;
        }
      }
    }
  } else {
#pragma unroll
    for (int mf = 0; mf < 8; ++mf)
#pragma unroll
      for (int jj = 0; jj < 4; ++jj) {
        const int m = m0 + (wr << 7) + mf * 16 + (lhi << 2) + jj;
        float* orow = dout + outBase + ((size_t)m << 11) + nsec + l15;
#pragma unroll
        for (int nf = 0; nf < 4; ++nf) orow[nf << 4] = acc[mf][nf][jj] + biasv[nf];
      }
  }
}

extern "C" void kernel_launch(void* const* d_in, const int* in_sizes, int n_in,
                              void* d_out, int out_size, void* d_ws, size_t ws_size,
                              hipStream_t stream) {
  const float* x = (const float*)d_in[0];
  const float* rope = (const float*)d_in[1];
  const float* wq = (const float*)d_in[2];
  const float* bq = (const float*)d_in[3];
  const float* wk = (const float*)d_in[4];
  const float* bk = (const float*)d_in[5];
  const float* wv = (const float*)d_in[6];
  const float* bv = (const float*)d_in[7];
  const float* qnw = (const float*)d_in[8];
  const float* knw = (const float*)d_in[9];

  unsigned short* xbf = (unsigned short*)d_ws;                 // 32 MB
  unsigned short* wbf = xbf + (size_t)M_DIM * K_DIM;           // 24 MB

  cvt_all<<<2048, 256, 0, stream>>>(x, wq, wk, wv, xbf, wbf);

  gemm_fused<<<(M_DIM / 256) * (N_DIM / 256), 512, 0, stream>>>(
      xbf, wbf, rope, bq, bk, bv, qnw, knw, (float*)d_out);
}